// Round 2
// baseline (305.396 us; speedup 1.0000x reference)
//
#include <hip/hip_runtime.h>

#define NB 32
#define TT 512
#define UU 100
#define UM 101   // U+1
#define VV 4096
#define NEG (-1e30f)
#define PD 8     // prefetch distance (diagonals)

__device__ __forceinline__ float lae(float a, float b) {
    float m  = fmaxf(a, b);
    float nd = -fabsf(a - b);
    return m + __logf(1.0f + __expf(nd));
}

// Kernel A: em[n][j][t] = enc[n,t,y[n,j]] + dec[n,j,y[n,j]]  (emit edge entering u=j+1)
//           blk[n][t]   = enc[n,t,0]                          (contiguous blank row)
__global__ void emit_gather_k(const float* __restrict__ enc,
                              const float* __restrict__ dec,
                              const int* __restrict__ tgt,
                              const int* __restrict__ ilen,
                              const int* __restrict__ tlen,
                              float* __restrict__ em,
                              float* __restrict__ blk) {
    int nu = blockIdx.x;
    int n = nu / UU, j = nu % UU;
    const float* encn = enc + (size_t)n * TT * VV;
    if (j == 0) {   // one block per n also emits the contiguous blank copy
        for (int t = threadIdx.x; t < TT; t += blockDim.x)
            blk[n * TT + t] = encn[(size_t)t * VV];
    }
    if (j >= tlen[n]) return;          // never an ancestor of the target cell
    int tin = ilen[n];
    int y = tgt[n * UU + j];
    float dval = dec[((size_t)n * UM + j) * VV + y];
    const float* ep = encn + y;
    float* op = em + ((size_t)n * UU + j) * TT;
    for (int t = threadIdx.x; t < tin; t += blockDim.x)
        op[t] = ep[(size_t)t * VV] + dval;
}

// Kernel B: anti-diagonal wavefront DP, one 64-lane wave per batch element.
// lane L owns u = L (slot0) and u = L + 64 (slot1).
// All streams (emit, blank) are global loads prefetched PD diagonals ahead in
// register rings; only DS ops in the loop are the two bpermutes.
__global__ __launch_bounds__(64) void dp_k(const float* __restrict__ dec,
                                           const int* __restrict__ ilen,
                                           const int* __restrict__ tlen,
                                           const float* __restrict__ em,
                                           const float* __restrict__ blk,
                                           float* __restrict__ out) {
    int n = blockIdx.x;
    int lane = threadIdx.x;
    int tin = ilen[n], tg = tlen[n];
    int u0 = lane, u1 = lane + 64;

    const float* decn = dec + (size_t)n * UM * VV;
    float bd0 = decn[(size_t)u0 * VV];                         // dec[n][u0][BLANK]
    float bd1 = (u1 < UM) ? decn[(size_t)u1 * VV] : 0.0f;
    const float* em0 = em + ((size_t)n * UU + (u0 - 1)) * TT;  // deref only if u0>=1
    const float* em1 = em + ((size_t)n * UU + (u1 - 1)) * TT;
    const float* bl  = blk + n * TT;

    bool v0e = (u0 >= 1) && (u0 <= tg);
    bool v1e = (u1 <= tg);

    // stream fetchers for diagonal dd (cell t = dd - u); NEG when edge invalid
    auto E0 = [&](int dd) { int t = dd - u0; return (v0e && t >= 0 && t < tin) ? em0[t] : NEG; };
    auto E1 = [&](int dd) { int t = dd - u1; return (v1e && t >= 0 && t < tin) ? em1[t] : NEG; };
    auto B0 = [&](int dd) { int t = dd - u0; return (t >= 1 && t < TT) ? bl[t - 1] + bd0 : NEG; };
    auto B1 = [&](int dd) { int t = dd - u1; return (t >= 1 && t < TT) ? bl[t - 1] + bd1 : NEG; };

    float e0r[PD], e1r[PD], b0r[PD], b1r[PD];
#pragma unroll
    for (int k = 0; k < PD; ++k) {
        e0r[k] = E0(1 + k); e1r[k] = E1(1 + k);
        b0r[k] = B0(1 + k); b1r[k] = B1(1 + k);
    }

    float a0 = (lane == 0) ? 0.0f : NEG;   // alpha[0,0] = 0 at diagonal d=0
    float a1 = NEG;
    int dend = (tin - 1) + tg;
    float res = NEG;
    int paddr = ((lane - 1) & 63) << 2;    // bpermute byte address of lane-1 (wraps)

    for (int d = 1; d <= dend; d += PD) {
        // refill temporaries for diagonals d+PD .. d+2PD-1 (issued early, used next block)
        float te0[PD], te1[PD], tb0[PD], tb1[PD];
#pragma unroll
        for (int k = 0; k < PD; ++k) {
            te0[k] = E0(d + PD + k); te1[k] = E1(d + PD + k);
            tb0[k] = B0(d + PD + k); tb1[k] = B1(d + PD + k);
        }
        // process diagonals d .. d+PD-1 from the rings
#pragma unroll
        for (int k = 0; k < PD; ++k) {
            int dd = d + k;
            float l0 = __int_as_float(__builtin_amdgcn_ds_bpermute(paddr, __float_as_int(a0)));
            float sel = (lane == 63) ? a0 : a1;   // seam: u=64's left neighbor is u=63
            float l1 = __int_as_float(__builtin_amdgcn_ds_bpermute(paddr, __float_as_int(sel)));
            float bt0 = a0 + b0r[k];
            float bt1 = a1 + b1r[k];
            float et0 = l0 + e0r[k];
            float et1 = l1 + e1r[k];
            a0 = lae(bt0, et0);   // out-of-range cells carry finite junk; exp underflow
            a1 = lae(bt1, et1);   // makes the first in-range cell exact
            if (dd == dend) {
                if (u0 == tg) res = a0;
                if (u1 == tg) res = a1;
            }
        }
#pragma unroll
        for (int k = 0; k < PD; ++k) {
            e0r[k] = te0[k]; e1r[k] = te1[k];
            b0r[k] = tb0[k]; b1r[k] = tb1[k];
        }
    }

    float fin = bl[tin - 1];
    if (u0 == tg)      out[n] = res + fin + bd0;
    else if (u1 == tg) out[n] = res + fin + bd1;
}

extern "C" void kernel_launch(void* const* d_in, const int* in_sizes, int n_in,
                              void* d_out, int out_size, void* d_ws, size_t ws_size,
                              hipStream_t stream) {
    const float* enc  = (const float*)d_in[0];
    const float* dec  = (const float*)d_in[1];
    const int*   tgt  = (const int*)d_in[2];
    const int*   ilen = (const int*)d_in[3];
    const int*   tlen = (const int*)d_in[4];
    float* out = (float*)d_out;
    float* em  = (float*)d_ws;                       // N*UU*TT floats = 6.55 MB
    float* blk = em + (size_t)NB * UU * TT;          // N*TT floats   = 64 KB

    hipLaunchKernelGGL(emit_gather_k, dim3(NB * UU), dim3(256), 0, stream,
                       enc, dec, tgt, ilen, tlen, em, blk);
    hipLaunchKernelGGL(dp_k, dim3(NB), dim3(64), 0, stream,
                       dec, ilen, tlen, em, blk, out);
}

// Round 3
// 119.405 us; speedup vs baseline: 2.5576x; 2.5576x over previous
//
#include <hip/hip_runtime.h>

#define NB 32
#define TT 512
#define UU 100
#define UM 101   // U+1
#define VV 4096
#define NEG (-1e30f)
#define PD 16
#define DMAX 672
#define L2E 1.4426950408889634f
#define LN2 0.6931471805599453f

__device__ __forceinline__ float vexp2(float x){ float r; asm("v_exp_f32 %0, %1" : "=v"(r) : "v"(x)); return r; }
__device__ __forceinline__ float vlog2(float x){ float r; asm("v_log_f32 %0, %1" : "=v"(r) : "v"(x)); return r; }

// logaddexp in log2 domain
__device__ __forceinline__ float lae2(float a, float b) {
    float m  = fmaxf(a, b);
    float nd = -fabsf(a - b);
    return m + vlog2(1.0f + vexp2(nd));
}

// ---------- fast path: diagonal-major precomputed streams ----------

// blk[n][t] = enc[n][t][0]*L2E ; bdv[n][slot*64+lane] = dec[n][2*lane+slot][0]*L2E
__global__ void blk_k(const float* __restrict__ enc, const float* __restrict__ dec,
                      float* __restrict__ blk, float* __restrict__ bdv) {
    int n = blockIdx.x, tid = threadIdx.x;      // 512 threads
    blk[n * TT + tid] = enc[((size_t)n * TT + tid) * VV] * L2E;
    if (tid < 128) {
        int slot = tid >> 6, lane = tid & 63;
        int u = 2 * lane + slot;
        bdv[n * 128 + tid] = (u < UM) ? dec[((size_t)n * UM + u) * VV] * L2E : 0.0f;
    }
}

// stream[n][d][p] = {e=NEG, b = blank edge into cell (t=d-u, u)}, u = 2*(p&63)+(p>>6)
__global__ void fill_k(const float* __restrict__ blk, const float* __restrict__ bdv,
                       float2* __restrict__ st) {
    int n = blockIdx.y;
    int d = blockIdx.x * 2 + (threadIdx.x >> 7);
    int p = threadIdx.x & 127;
    int slot = p >> 6, lane = p & 63;
    int u = 2 * lane + slot;
    int t = d - u;
    float b = (t >= 1 && t < TT) ? blk[n * TT + (t - 1)] + bdv[n * 128 + p] : NEG;
    st[((size_t)n * DMAX + d) * 128 + p] = make_float2(NEG, b);
}

// overwrite e field: edge into u=j+1 at cell (t,u), diagonal d=t+u
__global__ void scat_k(const float* __restrict__ enc, const float* __restrict__ dec,
                       const int* __restrict__ tgt, const int* __restrict__ ilen,
                       const int* __restrict__ tlen, float* __restrict__ stx) {
    int nu = blockIdx.x;
    int n = nu / UU, j = nu % UU;
    if (j >= tlen[n]) return;
    int tin = ilen[n];
    int y = tgt[n * UU + j];
    float dval = dec[((size_t)n * UM + j) * VV + y];
    const float* ep = enc + (size_t)n * TT * VV + y;
    int u = j + 1, slot = u & 1, lane = u >> 1;
    float* op = stx + (((size_t)n * DMAX) * 128 + slot * 64 + lane) * 2;  // .x at d=0
    for (int t = threadIdx.x; t < tin; t += blockDim.x) {
        int d = t + u;
        op[(size_t)d * 256] = (ep[(size_t)t * VV] + dval) * L2E;
    }
}

// wavefront DP: lane L owns u=2L (slot0) and u=2L+1 (slot1).
// u=2L+1's left neighbor (u=2L) is same-lane a0; u=2L's is lane L-1's a1 (DPP shift).
__global__ __launch_bounds__(64) void dp_k(const float* __restrict__ bdv,
                                           const float* __restrict__ blk,
                                           const int* __restrict__ ilen,
                                           const int* __restrict__ tlen,
                                           const float2* __restrict__ st,
                                           float* __restrict__ out) {
    int n = blockIdx.x;
    int lane = threadIdx.x;
    int tin = ilen[n], tg = tlen[n];
    int dend = tin - 1 + tg;
    float bd0 = bdv[n * 128 + lane];
    float bd1 = bdv[n * 128 + 64 + lane];
    const float2* sp = st + ((size_t)n * DMAX) * 128 + lane;
    bool cap0 = (2 * lane == tg), cap1 = (2 * lane + 1 == tg);
    bool fx16 = (lane == 16), fx32 = (lane == 32), fx48 = (lane == 48);

    float a0 = (lane == 0) ? 0.0f : NEG;   // alpha[0][0]=0 at d=0
    float a1 = NEG;
    float res = NEG;

    auto STEP = [&](float2 v0, float2 v1, int dd) {
        int sh = __builtin_amdgcn_update_dpp(__float_as_int(NEG), __float_as_int(a1),
                                             0x111, 0xF, 0xF, false);   // row_shr:1
        float s15 = __int_as_float(__builtin_amdgcn_readlane(__float_as_int(a1), 15));
        float s31 = __int_as_float(__builtin_amdgcn_readlane(__float_as_int(a1), 31));
        float s47 = __int_as_float(__builtin_amdgcn_readlane(__float_as_int(a1), 47));
        float l0 = __int_as_float(sh);
        l0 = fx16 ? s15 : l0;
        l0 = fx32 ? s31 : l0;
        l0 = fx48 ? s47 : l0;
        float bt0 = a0 + v0.y, et0 = l0 + v0.x;
        float bt1 = a1 + v1.y, et1 = a0 + v1.x;   // et1 uses old a0
        a0 = lae2(bt0, et0);
        a1 = lae2(bt1, et1);
        if (dd == dend) { if (cap0) res = a0; if (cap1) res = a1; }
    };

    float2 A0[PD], A1[PD], B0[PD], B1[PD];
#pragma unroll
    for (int k = 0; k < PD; ++k) {
        A0[k] = sp[(size_t)(1 + k) * 128];
        A1[k] = sp[(size_t)(1 + k) * 128 + 64];
    }
    for (int d = 1; d <= dend; d += 2 * PD) {
#pragma unroll
        for (int k = 0; k < PD; ++k) {
            B0[k] = sp[(size_t)(d + PD + k) * 128];
            B1[k] = sp[(size_t)(d + PD + k) * 128 + 64];
        }
#pragma unroll
        for (int k = 0; k < PD; ++k) STEP(A0[k], A1[k], d + k);
#pragma unroll
        for (int k = 0; k < PD; ++k) {
            A0[k] = sp[(size_t)(d + 2 * PD + k) * 128];
            A1[k] = sp[(size_t)(d + 2 * PD + k) * 128 + 64];
        }
#pragma unroll
        for (int k = 0; k < PD; ++k) STEP(B0[k], B1[k], d + PD + k);
    }
    float fin = blk[n * TT + (tin - 1)];
    if (cap0) out[n] = (res + fin + bd0) * LN2;
    if (cap1) out[n] = (res + fin + bd1) * LN2;
}

// ---------- fallback path (R2, known-good) if ws too small ----------

__device__ __forceinline__ float lae_fb(float a, float b) {
    float m  = fmaxf(a, b);
    float nd = -fabsf(a - b);
    return m + __logf(1.0f + __expf(nd));
}

__global__ void gather_fb_k(const float* __restrict__ enc, const float* __restrict__ dec,
                            const int* __restrict__ tgt, const int* __restrict__ ilen,
                            const int* __restrict__ tlen,
                            float* __restrict__ em, float* __restrict__ blk) {
    int nu = blockIdx.x;
    int n = nu / UU, j = nu % UU;
    const float* encn = enc + (size_t)n * TT * VV;
    if (j == 0) {
        for (int t = threadIdx.x; t < TT; t += blockDim.x)
            blk[n * TT + t] = encn[(size_t)t * VV];
    }
    if (j >= tlen[n]) return;
    int tin = ilen[n];
    int y = tgt[n * UU + j];
    float dval = dec[((size_t)n * UM + j) * VV + y];
    const float* ep = encn + y;
    float* op = em + ((size_t)n * UU + j) * TT;
    for (int t = threadIdx.x; t < tin; t += blockDim.x)
        op[t] = ep[(size_t)t * VV] + dval;
}

__global__ __launch_bounds__(64) void dp_fb_k(const float* __restrict__ dec,
                                              const int* __restrict__ ilen,
                                              const int* __restrict__ tlen,
                                              const float* __restrict__ em,
                                              const float* __restrict__ blk,
                                              float* __restrict__ out) {
    int n = blockIdx.x;
    int lane = threadIdx.x;
    int tin = ilen[n], tg = tlen[n];
    int u0 = lane, u1 = lane + 64;
    const float* decn = dec + (size_t)n * UM * VV;
    float bd0 = decn[(size_t)u0 * VV];
    float bd1 = (u1 < UM) ? decn[(size_t)u1 * VV] : 0.0f;
    const float* em0 = em + ((size_t)n * UU + (u0 - 1)) * TT;
    const float* em1 = em + ((size_t)n * UU + (u1 - 1)) * TT;
    const float* bl  = blk + n * TT;
    bool v0e = (u0 >= 1) && (u0 <= tg);
    bool v1e = (u1 <= tg);
    auto E0 = [&](int dd) { int t = dd - u0; return (v0e && t >= 0 && t < tin) ? em0[t] : NEG; };
    auto E1 = [&](int dd) { int t = dd - u1; return (v1e && t >= 0 && t < tin) ? em1[t] : NEG; };
    auto Bb0 = [&](int dd) { int t = dd - u0; return (t >= 1 && t < TT) ? bl[t - 1] + bd0 : NEG; };
    auto Bb1 = [&](int dd) { int t = dd - u1; return (t >= 1 && t < TT) ? bl[t - 1] + bd1 : NEG; };
    float a0 = (lane == 0) ? 0.0f : NEG;
    float a1 = NEG;
    int dend = (tin - 1) + tg;
    float res = NEG;
    int paddr = ((lane - 1) & 63) << 2;
    for (int d = 1; d <= dend; ++d) {
        float e0 = E0(d), e1 = E1(d), b0 = Bb0(d), b1 = Bb1(d);
        float l0 = __int_as_float(__builtin_amdgcn_ds_bpermute(paddr, __float_as_int(a0)));
        float sel = (lane == 63) ? a0 : a1;
        float l1 = __int_as_float(__builtin_amdgcn_ds_bpermute(paddr, __float_as_int(sel)));
        a0 = lae_fb(a0 + b0, l0 + e0);
        a1 = lae_fb(a1 + b1, l1 + e1);
        if (d == dend) {
            if (u0 == tg) res = a0;
            if (u1 == tg) res = a1;
        }
    }
    float fin = bl[tin - 1];
    if (u0 == tg)      out[n] = res + fin + bd0;
    else if (u1 == tg) out[n] = res + fin + bd1;
}

extern "C" void kernel_launch(void* const* d_in, const int* in_sizes, int n_in,
                              void* d_out, int out_size, void* d_ws, size_t ws_size,
                              hipStream_t hs) {
    const float* enc  = (const float*)d_in[0];
    const float* dec  = (const float*)d_in[1];
    const int*   tgt  = (const int*)d_in[2];
    const int*   ilen = (const int*)d_in[3];
    const int*   tlen = (const int*)d_in[4];
    float* out = (float*)d_out;

    size_t need = (size_t)NB * DMAX * 128 * sizeof(float2)
                + (size_t)NB * TT * sizeof(float)
                + (size_t)NB * 128 * sizeof(float);
    if (ws_size >= need) {
        float2* st  = (float2*)d_ws;
        float*  blk = (float*)(st + (size_t)NB * DMAX * 128);
        float*  bdv = blk + NB * TT;
        hipLaunchKernelGGL(blk_k,  dim3(NB), dim3(512), 0, hs, enc, dec, blk, bdv);
        hipLaunchKernelGGL(fill_k, dim3(DMAX / 2, NB), dim3(256), 0, hs, blk, bdv, st);
        hipLaunchKernelGGL(scat_k, dim3(NB * UU), dim3(512), 0, hs,
                           enc, dec, tgt, ilen, tlen, (float*)st);
        hipLaunchKernelGGL(dp_k,   dim3(NB), dim3(64), 0, hs, bdv, blk, ilen, tlen, st, out);
    } else {
        float* em  = (float*)d_ws;
        float* blk = em + (size_t)NB * UU * TT;
        hipLaunchKernelGGL(gather_fb_k, dim3(NB * UU), dim3(256), 0, hs,
                           enc, dec, tgt, ilen, tlen, em, blk);
        hipLaunchKernelGGL(dp_fb_k, dim3(NB), dim3(64), 0, hs,
                           dec, ilen, tlen, em, blk, out);
    }
}

// Round 4
// 83.007 us; speedup vs baseline: 3.6792x; 1.4385x over previous
//
#include <hip/hip_runtime.h>

#define NB 32
#define TT 512
#define UU 100
#define UM 101   // U+1
#define VV 4096
#define NEG (-1e30f)
#define PD 16
#define DMAX 672
#define L2E 1.4426950408889634f
#define LN2 0.6931471805599453f

__device__ __forceinline__ float vexp2(float x){ float r; asm("v_exp_f32 %0, %1" : "=v"(r) : "v"(x)); return r; }
__device__ __forceinline__ float vlog2(float x){ float r; asm("v_log_f32 %0, %1" : "=v"(r) : "v"(x)); return r; }

// logaddexp in log2 domain
__device__ __forceinline__ float lae2(float a, float b) {
    float m  = fmaxf(a, b);
    float nd = -fabsf(a - b);
    return m + vlog2(1.0f + vexp2(nd));
}

// prep: blk[n][t] = enc[n][t][0]*L2E ; bdv[n][u] = dec[n][u][0]*L2E ;
//       dvx[n][j] = dec[n][j][y[n][j]]*L2E
__global__ void prep_k(const float* __restrict__ enc, const float* __restrict__ dec,
                       const int* __restrict__ tgt,
                       float* __restrict__ blk, float* __restrict__ bdv,
                       float* __restrict__ dvx) {
    int n = blockIdx.x, tid = threadIdx.x;   // 512 threads
    blk[n * TT + tid] = enc[((size_t)n * TT + tid) * VV] * L2E;
    if (tid < UM) bdv[n * UM + tid] = dec[((size_t)n * UM + tid) * VV] * L2E;
    if (tid < UU) {
        int y = tgt[n * UU + tid];
        dvx[n * UU + tid] = dec[((size_t)n * UM + tid) * VV + y] * L2E;
    }
}

// build the full diagonal-major stream in ONE pass with coalesced float4 writes.
// st[n][d][lane] = {e(u=2L), b(u=2L), e(u=2L+1), b(u=2L+1)}, t = d - u.
__global__ void build_k(const float* __restrict__ enc, const int* __restrict__ tgt,
                        const int* __restrict__ ilen, const int* __restrict__ tlen,
                        const float* __restrict__ blk, const float* __restrict__ bdv,
                        const float* __restrict__ dvx, float4* __restrict__ st) {
    int n = blockIdx.y;
    int d = blockIdx.x * 4 + (threadIdx.x >> 6);
    int lane = threadIdx.x & 63;
    int tin = ilen[n], tg = tlen[n];
    const float* encn = enc + (size_t)n * TT * VV;
    float4 v;
    {   // slot 0: u = 2*lane
        int u = 2 * lane, t = d - u;
        float e = NEG, b = NEG;
        if (u >= 1 && u <= tg && t >= 0 && t < tin)
            e = fmaf(encn[(size_t)t * VV + tgt[n * UU + u - 1]], L2E, dvx[n * UU + u - 1]);
        if (u <= UU && t >= 1 && t < TT)
            b = blk[n * TT + t - 1] + bdv[n * UM + u];
        v.x = e; v.y = b;
    }
    {   // slot 1: u = 2*lane + 1  (u >= 1 always)
        int u = 2 * lane + 1, t = d - u;
        float e = NEG, b = NEG;
        if (u <= tg && t >= 0 && t < tin)
            e = fmaf(encn[(size_t)t * VV + tgt[n * UU + u - 1]], L2E, dvx[n * UU + u - 1]);
        if (u <= UU && t >= 1 && t < TT)
            b = blk[n * TT + t - 1] + bdv[n * UM + u];
        v.z = e; v.w = b;
    }
    st[((size_t)n * DMAX + d) * 64 + lane] = v;
}

// wavefront DP: lane L owns u=2L (slot0, a0) and u=2L+1 (slot1, a1).
// One float4 load per diagonal; register rings pinned by sched_barrier(0).
__global__ __launch_bounds__(64) void dp_k(const int* __restrict__ ilen,
                                           const int* __restrict__ tlen,
                                           const float4* __restrict__ st,
                                           const float* __restrict__ blk,
                                           const float* __restrict__ bdv,
                                           float* __restrict__ out) {
    int n = blockIdx.x;
    int lane = threadIdx.x;
    int tin = ilen[n], tg = tlen[n];
    int dend = tin - 1 + tg;
    const float4* sp = st + ((size_t)n * DMAX) * 64 + lane;
    bool cap0 = (2 * lane == tg), cap1 = (2 * lane + 1 == tg);
    bool fx16 = (lane == 16), fx32 = (lane == 32), fx48 = (lane == 48);

    float a0 = (lane == 0) ? 0.0f : NEG;   // alpha[0][0] = 0 at d=0
    float a1 = NEG;
    float res = NEG;

    auto STEP = [&](float4 v, int dd) {
        // left neighbor of u=2L is lane L-1's a1: DPP row_shr:1 + row-seam fixups
        int sh = __builtin_amdgcn_update_dpp(__float_as_int(NEG), __float_as_int(a1),
                                             0x111, 0xF, 0xF, false);   // row_shr:1
        float s15 = __int_as_float(__builtin_amdgcn_readlane(__float_as_int(a1), 15));
        float s31 = __int_as_float(__builtin_amdgcn_readlane(__float_as_int(a1), 31));
        float s47 = __int_as_float(__builtin_amdgcn_readlane(__float_as_int(a1), 47));
        float l0 = __int_as_float(sh);
        l0 = fx16 ? s15 : l0;
        l0 = fx32 ? s31 : l0;
        l0 = fx48 ? s47 : l0;
        float bt0 = a0 + v.y, et0 = l0 + v.x;
        float bt1 = a1 + v.w, et1 = a0 + v.z;   // u=2L+1's left neighbor: same-lane old a0
        a0 = lae2(bt0, et0);
        a1 = lae2(bt1, et1);
        if (dd == dend) { if (cap0) res = a0; if (cap1) res = a1; }
    };

    float4 A[PD], B[PD];
#pragma unroll
    for (int k = 0; k < PD; ++k) A[k] = sp[(size_t)(1 + k) * 64];
    __builtin_amdgcn_sched_barrier(0);

    for (int d = 1; d <= dend; d += 2 * PD) {
#pragma unroll
        for (int k = 0; k < PD; ++k) B[k] = sp[(size_t)(d + PD + k) * 64];
        __builtin_amdgcn_sched_barrier(0);
#pragma unroll
        for (int k = 0; k < PD; ++k) STEP(A[k], d + k);
        __builtin_amdgcn_sched_barrier(0);
#pragma unroll
        for (int k = 0; k < PD; ++k) A[k] = sp[(size_t)(d + 2 * PD + k) * 64];
        __builtin_amdgcn_sched_barrier(0);
#pragma unroll
        for (int k = 0; k < PD; ++k) STEP(B[k], d + PD + k);
        __builtin_amdgcn_sched_barrier(0);
    }

    float fin  = blk[n * TT + (tin - 1)];
    float bdtg = bdv[n * UM + tg];
    if (cap0 | cap1) out[n] = (res + fin + bdtg) * LN2;
}

extern "C" void kernel_launch(void* const* d_in, const int* in_sizes, int n_in,
                              void* d_out, int out_size, void* d_ws, size_t ws_size,
                              hipStream_t hs) {
    const float* enc  = (const float*)d_in[0];
    const float* dec  = (const float*)d_in[1];
    const int*   tgt  = (const int*)d_in[2];
    const int*   ilen = (const int*)d_in[3];
    const int*   tlen = (const int*)d_in[4];
    float* out = (float*)d_out;

    float4* st  = (float4*)d_ws;                          // 22 MB
    float*  blk = (float*)(st + (size_t)NB * DMAX * 64);  // 64 KB
    float*  bdv = blk + NB * TT;                          // 12.9 KB
    float*  dvx = bdv + NB * UM;                          // 12.8 KB

    hipLaunchKernelGGL(prep_k,  dim3(NB), dim3(512), 0, hs, enc, dec, tgt, blk, bdv, dvx);
    hipLaunchKernelGGL(build_k, dim3(DMAX / 4, NB), dim3(256), 0, hs,
                       enc, tgt, ilen, tlen, blk, bdv, dvx, st);
    hipLaunchKernelGGL(dp_k,    dim3(NB), dim3(64), 0, hs, ilen, tlen, st, blk, bdv, out);
}